// Round 3
// baseline (248.020 us; speedup 1.0000x reference)
//
#include <hip/hip_runtime.h>

typedef unsigned short ushort_t;
typedef short bf16x8 __attribute__((ext_vector_type(8)));
typedef float f32x4 __attribute__((ext_vector_type(4)));

#define MFMA(a, b, c) __builtin_amdgcn_mfma_f32_16x16x32_bf16(a, b, c, 0, 0, 0)

#define B_    32
#define HW_   3136
#define NPOS  100352

__device__ __forceinline__ float bf2f(unsigned short h) {
    return __uint_as_float(((unsigned int)h) << 16);
}
__device__ __forceinline__ unsigned short f2bf(float f) {
    unsigned int u = __float_as_uint(f);
    u += 0x7FFFu + ((u >> 16) & 1u);
    return (unsigned short)(u >> 16);
}
__device__ __forceinline__ float qgelu(float v) {
    return v / (1.0f + __expf(-1.702f * v));
}
__device__ __forceinline__ void unpack8(uint4 v, float* f) {
    f[0] = bf2f((unsigned short)(v.x & 0xffff)); f[1] = bf2f((unsigned short)(v.x >> 16));
    f[2] = bf2f((unsigned short)(v.y & 0xffff)); f[3] = bf2f((unsigned short)(v.y >> 16));
    f[4] = bf2f((unsigned short)(v.z & 0xffff)); f[5] = bf2f((unsigned short)(v.z >> 16));
    f[6] = bf2f((unsigned short)(v.w & 0xffff)); f[7] = bf2f((unsigned short)(v.w >> 16));
}

// ---------------------------------------------------------------------------
// K0: pack weights into MFMA B-fragment order (bf16).
// B-frag for (kc,nt): lane holds B[k=kc*32+(lane>>4)*8+j][n=nt*16+(lane&15)].
// Stored flat: [frag-linear][lane][8].
// ---------------------------------------------------------------------------
__global__ __launch_bounds__(256) void k0_prep(
    const float* __restrict__ W1, const float* __restrict__ W2,
    const float* __restrict__ mtok, const float* __restrict__ Wd,
    const float* __restrict__ Wu,
    ushort_t* __restrict__ w1f, ushort_t* __restrict__ wdf,
    ushort_t* __restrict__ w2f, ushort_t* __restrict__ mtf,
    ushort_t* __restrict__ wuf)
{
    const int gid = blockIdx.x * 256 + threadIdx.x;
    const int stride = gridDim.x * 256;
    // W1 / Wd: K=192 (6 kc) x N=64 (4 nt): 6*4*64*8 = 12288
    for (int i = gid; i < 12288; i += stride) {
        int j = i & 7, lane = (i >> 3) & 63, nt = (i >> 9) & 3, kc = i >> 11;
        int n = nt * 16 + (lane & 15), k = kc * 32 + (lane >> 4) * 8 + j;
        w1f[i] = f2bf(W1[n * 192 + k]);
        wdf[i] = f2bf(Wd[n * 192 + k]);
    }
    // W2: K=64 (2 kc) x N=64 (4 nt): 4096
    for (int i = gid; i < 4096; i += stride) {
        int j = i & 7, lane = (i >> 3) & 63, nt = (i >> 9) & 3, kc = i >> 11;
        int n = nt * 16 + (lane & 15), k = kc * 32 + (lane >> 4) * 8 + j;
        w2f[i] = f2bf(W2[n * 64 + k]);
    }
    // mask_token: K=64 (2 kc) x N=8 padded to 16: 2*64*8 = 1024
    for (int i = gid; i < 1024; i += stride) {
        int j = i & 7, lane = (i >> 3) & 63, kc = i >> 9;
        int n = lane & 15, k = kc * 32 + (lane >> 4) * 8 + j;
        mtf[i] = (n < 8) ? f2bf(mtok[n * 64 + k]) : (ushort_t)0;
    }
    // Wu: K=64 (2 kc) x N=192 (12 nt): 2*12*64*8 = 12288
    for (int i = gid; i < 12288; i += stride) {
        int j = i & 7, lane = (i >> 3) & 63, g = i >> 9;
        int nt = g % 12, kc = g / 12;
        int n = nt * 16 + (lane & 15), k = kc * 32 + (lane >> 4) * 8 + j;
        wuf[i] = f2bf(Wu[n * 64 + k]);
    }
}

// ---------------------------------------------------------------------------
// K1 (MFMA), v3: weights staged in LDS (kills 58 serialized global
// B-loads/wave -> ds_read_b128). x A-frag loads issued BEFORE the staging
// barrier so their latency hides under staging. Single per-wave LDS buffer,
// sequenced: pf1 -> GEMM2 -> xp -> store xp -> pf2 -> logits -> store pf2.
// LDS: 59,392 (weights) + 9,216 (bufs) = 68,608 B -> 2 blocks/CU (8 waves).
// __launch_bounds__(256,2): VGPR cap 128 so the compiler can prefetch.
// ---------------------------------------------------------------------------
__global__ __launch_bounds__(256, 2) void k1_meta_adapter(
    const float* __restrict__ x, const float* __restrict__ b1,
    const float* __restrict__ b2, const float* __restrict__ bd,
    const ushort_t* __restrict__ w1f, const ushort_t* __restrict__ wdf,
    const ushort_t* __restrict__ w2f, const ushort_t* __restrict__ mtf,
    ushort_t* __restrict__ pf2g, ushort_t* __restrict__ xpg,
    float* __restrict__ Lg)
{
    __shared__ ushort_t wsh[29696];       // w1[0,12288) wd[12288,24576) w2[24576,28672) mt[28672,29696)
    __shared__ ushort_t buf[4][16 * 72];  // per-wave buffer (9,216 B)

    const int tid = threadIdx.x;
    const int lane = tid & 63, wv = tid >> 6;
    const int col = lane & 15, q = lane >> 4;
    const int posBase = blockIdx.x * 64;
    const float* xrow = x + (size_t)(posBase + wv * 16 + col) * 192;

    // issue x loads first (12 independent float4 loads; latency hides under staging)
    float4 xv[6][2];
    #pragma unroll
    for (int kc = 0; kc < 6; kc++) {
        const float4* gp = (const float4*)(xrow + kc * 32 + q * 8);
        xv[kc][0] = gp[0]; xv[kc][1] = gp[1];
    }

    // stage weight fragments -> LDS (3,712 uint4 total)
    {
        uint4* d = (uint4*)wsh;
        const uint4* s1 = (const uint4*)w1f;
        for (int u = tid; u < 1536; u += 256) d[u] = s1[u];
        uint4* d2 = (uint4*)(wsh + 12288);
        const uint4* s2 = (const uint4*)wdf;
        for (int u = tid; u < 1536; u += 256) d2[u] = s2[u];
        uint4* d3 = (uint4*)(wsh + 24576);
        const uint4* s3 = (const uint4*)w2f;
        for (int u = tid; u < 512; u += 256) d3[u] = s3[u];
        uint4* d4 = (uint4*)(wsh + 28672);
        const uint4* s4 = (const uint4*)mtf;
        if (tid < 128) d4[tid] = s4[tid];
    }

    // convert x -> bf16 A-frags while staging is in flight
    bf16x8 A[6];
    #pragma unroll
    for (int kc = 0; kc < 6; kc++) {
        float4 v0 = xv[kc][0], v1 = xv[kc][1];
        A[kc][0] = (short)f2bf(v0.x); A[kc][1] = (short)f2bf(v0.y);
        A[kc][2] = (short)f2bf(v0.z); A[kc][3] = (short)f2bf(v0.w);
        A[kc][4] = (short)f2bf(v1.x); A[kc][5] = (short)f2bf(v1.y);
        A[kc][6] = (short)f2bf(v1.z); A[kc][7] = (short)f2bf(v1.w);
    }
    __syncthreads();

    f32x4 acc1[4], acc3[4];
    #pragma unroll
    for (int nt = 0; nt < 4; nt++) { acc1[nt] = (f32x4)0.0f; acc3[nt] = (f32x4)0.0f; }

    // GEMM1 (x@W1^T) + GEMM3 (x@Wd^T), B-frags from LDS
    #pragma unroll
    for (int kc = 0; kc < 6; kc++) {
        #pragma unroll
        for (int nt = 0; nt < 4; nt++) {
            bf16x8 B1 = *(const bf16x8*)&wsh[((kc * 4 + nt) * 64 + lane) * 8];
            acc1[nt] = MFMA(A[kc], B1, acc1[nt]);
            bf16x8 Bd = *(const bf16x8*)&wsh[12288 + ((kc * 4 + nt) * 64 + lane) * 8];
            acc3[nt] = MFMA(A[kc], Bd, acc3[nt]);
        }
    }

    ushort_t* bA = &buf[wv][0];

    // pf1 = relu(acc1 + b1) -> buf
    #pragma unroll
    for (int nt = 0; nt < 4; nt++) {
        float bias = b1[nt * 16 + col];
        #pragma unroll
        for (int r = 0; r < 4; r++) {
            float v = acc1[nt][r] + bias;
            v = v > 0.0f ? v : 0.0f;
            bA[(q * 4 + r) * 72 + nt * 16 + col] = f2bf(v);
        }
    }

    // GEMM2: pf2 = pf1 @ W2^T (reads buf; same-wave in-order)
    f32x4 acc2[4];
    #pragma unroll
    for (int nt = 0; nt < 4; nt++) acc2[nt] = (f32x4)0.0f;
    #pragma unroll
    for (int kc = 0; kc < 2; kc++) {
        bf16x8 A2 = *(const bf16x8*)&bA[col * 72 + kc * 32 + q * 8];
        #pragma unroll
        for (int nt = 0; nt < 4; nt++) {
            bf16x8 B2 = *(const bf16x8*)&wsh[24576 + ((kc * 4 + nt) * 64 + lane) * 8];
            acc2[nt] = MFMA(A2, B2, acc2[nt]);
        }
    }

    // xp = qgelu(acc3 + bd) -> buf (pf1 dead)
    #pragma unroll
    for (int nt = 0; nt < 4; nt++) {
        float bias = bd[nt * 16 + col];
        #pragma unroll
        for (int r = 0; r < 4; r++) {
            float v = qgelu(acc3[nt][r] + bias);
            bA[(q * 4 + r) * 72 + nt * 16 + col] = f2bf(v);
        }
    }

    // write xp (per-wave coalesced: 16 pos x 8 chunks, 2/lane)
    #pragma unroll
    for (int t = 0; t < 2; t++) {
        int idx = lane + t * 64;
        int pos = idx >> 3, c8 = idx & 7;
        uint4 vx = *(const uint4*)&bA[pos * 72 + c8 * 8];
        *(uint4*)(xpg + ((size_t)(posBase + wv * 16 + pos)) * 64 + c8 * 8) = vx;
    }

    // pf2 (+b2) -> buf (xp dead)
    #pragma unroll
    for (int nt = 0; nt < 4; nt++) {
        float bias = b2[nt * 16 + col];
        #pragma unroll
        for (int r = 0; r < 4; r++)
            bA[(q * 4 + r) * 72 + nt * 16 + col] = f2bf(acc2[nt][r] + bias);
    }

    // logits: L = pf2 @ mtok^T (N=8 padded to 16)
    f32x4 Lacc = (f32x4)0.0f;
    #pragma unroll
    for (int kc = 0; kc < 2; kc++) {
        bf16x8 A3 = *(const bf16x8*)&bA[col * 72 + kc * 32 + q * 8];
        bf16x8 Bm = *(const bf16x8*)&wsh[28672 + (kc * 64 + lane) * 8];
        Lacc = MFMA(A3, Bm, Lacc);
    }
    if (col < 8) {
        #pragma unroll
        for (int r = 0; r < 4; r++)
            Lg[((size_t)(posBase + wv * 16 + q * 4 + r)) * 8 + col] = Lacc[r];
    }

    // write pf2
    #pragma unroll
    for (int t = 0; t < 2; t++) {
        int idx = lane + t * 64;
        int pos = idx >> 3, c8 = idx & 7;
        uint4 vp = *(const uint4*)&bA[pos * 72 + c8 * 8];
        *(uint4*)(pf2g + ((size_t)(posBase + wv * 16 + pos)) * 64 + c8 * 8) = vp;
    }
}

// ---------------------------------------------------------------------------
// K2a: per-(b, slice) partial softmax stats. 256 blocks (b = blk/8, sl = blk%8),
// 392 positions per slice. Writes Pmax/Psum [32][8][8].
// ---------------------------------------------------------------------------
__global__ __launch_bounds__(256) void k2a_partial(
    const float* __restrict__ Lg, float* __restrict__ Pmax, float* __restrict__ Psum)
{
    __shared__ float wred[4][8];
    __shared__ float Msh[8];

    const int tid = threadIdx.x;
    const int b = blockIdx.x >> 3, sl = blockIdx.x & 7;
    const int lane = tid & 63, wv = tid >> 6;
    const float* Lb = Lg + ((size_t)b * HW_ + (size_t)sl * 392) * 8;

    float l0[8], l1[8];
    {
        const float4* p = (const float4*)(Lb + (size_t)tid * 8);
        float4 a = p[0], c = p[1];
        l0[0] = a.x; l0[1] = a.y; l0[2] = a.z; l0[3] = a.w;
        l0[4] = c.x; l0[5] = c.y; l0[6] = c.z; l0[7] = c.w;
    }
    if (tid < 136) {
        const float4* p = (const float4*)(Lb + (size_t)(tid + 256) * 8);
        float4 a = p[0], c = p[1];
        l1[0] = a.x; l1[1] = a.y; l1[2] = a.z; l1[3] = a.w;
        l1[4] = c.x; l1[5] = c.y; l1[6] = c.z; l1[7] = c.w;
    } else {
        #pragma unroll
        for (int m = 0; m < 8; m++) l1[m] = -1e30f;
    }

    float lm[8];
    #pragma unroll
    for (int m = 0; m < 8; m++) {
        float v = fmaxf(l0[m], l1[m]);
        for (int off = 32; off > 0; off >>= 1) v = fmaxf(v, __shfl_down(v, off));
        lm[m] = v;
    }
    if (lane == 0) {
        #pragma unroll
        for (int m = 0; m < 8; m++) wred[wv][m] = lm[m];
    }
    __syncthreads();
    if (tid < 8)
        Msh[tid] = fmaxf(fmaxf(wred[0][tid], wred[1][tid]), fmaxf(wred[2][tid], wred[3][tid]));
    __syncthreads();

    float s[8];
    #pragma unroll
    for (int m = 0; m < 8; m++)
        s[m] = __expf(l0[m] - Msh[m]) + __expf(l1[m] - Msh[m]);   // l1=-1e30 -> 0
    #pragma unroll
    for (int m = 0; m < 8; m++) {
        float v = s[m];
        for (int off = 32; off > 0; off >>= 1) v += __shfl_down(v, off);
        s[m] = v;
    }
    __syncthreads();
    if (lane == 0) {
        #pragma unroll
        for (int m = 0; m < 8; m++) wred[wv][m] = s[m];
    }
    __syncthreads();
    if (tid < 8) {
        Psum[((size_t)b * 8 + sl) * 8 + tid] =
            wred[0][tid] + wred[1][tid] + wred[2][tid] + wred[3][tid];
        Pmax[((size_t)b * 8 + sl) * 8 + tid] = Msh[tid];
    }
}

// ---------------------------------------------------------------------------
// K2b: combine slice partials -> smx/sinv per (b,m); zero mwf. 1 block.
// ---------------------------------------------------------------------------
__global__ __launch_bounds__(256) void k2b_combine(
    const float* __restrict__ Pmax, const float* __restrict__ Psum,
    float* __restrict__ smxg, float* __restrict__ sinvg, float* __restrict__ mwfg)
{
    const int tid = threadIdx.x;        // 256 = 32 b x 8 m
    const int b = tid >> 3, m = tid & 7;
    float M = -1e30f;
    #pragma unroll
    for (int sl = 0; sl < 8; sl++)
        M = fmaxf(M, Pmax[((size_t)b * 8 + sl) * 8 + m]);
    float S = 0.0f;
    #pragma unroll
    for (int sl = 0; sl < 8; sl++)
        S += Psum[((size_t)b * 8 + sl) * 8 + m] * __expf(Pmax[((size_t)b * 8 + sl) * 8 + m] - M);
    smxg[tid] = M;
    sinvg[tid] = 1.0f / S;
    for (int i = tid; i < 2048; i += 256) mwfg[i] = 0.0f;
}

// ---------------------------------------------------------------------------
// K2c: masksum per slice + weighted pf2 reduction, atomicAdd into mwf.
// 256 blocks (b = blk/8, sl = blk%8).
// ---------------------------------------------------------------------------
__global__ __launch_bounds__(256) void k2c_mwf(
    const float* __restrict__ Lg, const ushort_t* __restrict__ pf2g,
    const float* __restrict__ smxg, const float* __restrict__ sinvg,
    float* __restrict__ mwfg)
{
    __shared__ float ms[392];
    __shared__ float sred[32 * 64];

    const int tid = threadIdx.x;
    const int b = blockIdx.x >> 3, sl = blockIdx.x & 7;
    const size_t base = (size_t)b * HW_ + (size_t)sl * 392;

    float smx[8], sinv[8];
    #pragma unroll
    for (int m = 0; m < 8; m++) {
        smx[m] = smxg[b * 8 + m];
        sinv[m] = sinvg[b * 8 + m];
    }

    for (int lp = tid; lp < 392; lp += 256) {
        const float4* p = (const float4*)(Lg + (base + lp) * 8);
        float4 a = p[0], c = p[1];
        ms[lp] = __expf(a.x - smx[0]) * sinv[0] + __expf(a.y - smx[1]) * sinv[1]
               + __expf(a.z - smx[2]) * sinv[2] + __expf(a.w - smx[3]) * sinv[3]
               + __expf(c.x - smx[4]) * sinv[4] + __expf(c.y - smx[5]) * sinv[5]
               + __expf(c.z - smx[6]) * sinv[6] + __expf(c.w - smx[7]) * sinv[7];
    }
    __syncthreads();

    const int part = tid >> 3, kg = tid & 7;
    float a8[8];
    #pragma unroll
    for (int j = 0; j < 8; j++) a8[j] = 0.0f;
    for (int lp = part; lp < 392; lp += 32) {
        float w = ms[lp];
        uint4 v = *(const uint4*)(pf2g + (base + lp) * 64 + kg * 8);
        float f[8]; unpack8(v, f);
        #pragma unroll
        for (int j = 0; j < 8; j++) a8[j] += w * f[j];
    }
    #pragma unroll
    for (int j = 0; j < 8; j++) sred[part * 64 + kg * 8 + j] = a8[j];
    __syncthreads();
    if (tid < 64) {
        float s = 0.0f;
        #pragma unroll
        for (int pt = 0; pt < 32; pt++) s += sred[pt * 64 + tid];
        atomicAdd(&mwfg[b * 64 + tid], s);
    }
}

// ---------------------------------------------------------------------------
// K3 v2: conv_w = mwf@Wh^T + bh in k4's B-frag order. 4-way b-split for
// occupancy: 576 blocks x 256 threads, thread = (op 64/block, b-quad 4).
// 2-accumulator inner loop breaks the serial FMA chain.
// ---------------------------------------------------------------------------
__global__ __launch_bounds__(256) void k3_hypernet(
    const float* __restrict__ mwfg, const float* __restrict__ Whg,
    const float* __restrict__ bhg, ushort_t* __restrict__ cwb)
{
    __shared__ float mwfs[32 * 64];
    const int tid = threadIdx.x;
    for (int i = tid; i < 2048; i += 256) mwfs[i] = mwfg[i];
    __syncthreads();

    const int op = blockIdx.x * 64 + (tid >> 2);   // 0..36863
    const int bq = tid & 3;                        // b-quad: b in [bq*8, bq*8+8)
    const int j = op & 7, lane = (op >> 3) & 63, nt = (op >> 9) & 3;
    const int kc = (op >> 11) & 1, tap = op >> 12;
    const int oc = nt * 16 + (lane & 15);
    const int ic = kc * 32 + (lane >> 4) * 8 + j;
    const int o = oc * 576 + ic * 9 + tap;     // Wh row

    float wreg[64];
    const float4* src = (const float4*)(Whg + (size_t)o * 64);
    #pragma unroll
    for (int t = 0; t < 16; t++) {
        float4 v = src[t];
        wreg[t * 4 + 0] = v.x; wreg[t * 4 + 1] = v.y;
        wreg[t * 4 + 2] = v.z; wreg[t * 4 + 3] = v.w;
    }
    const float bias = bhg[o];
    #pragma unroll
    for (int i = 0; i < 8; i += 2) {
        int b0 = bq * 8 + i, b1 = b0 + 1;
        float a0 = bias, a1 = bias;
        #pragma unroll
        for (int k = 0; k < 64; k++) {
            a0 += mwfs[b0 * 64 + k] * wreg[k];
            a1 += mwfs[b1 * 64 + k] * wreg[k];
        }
        cwb[(size_t)b0 * 36864 + op] = f2bf(a0);
        cwb[(size_t)b1 * 36864 + op] = f2bf(a1);
    }
}

// ---------------------------------------------------------------------------
// K4 (MFMA): per-sample 3x3 conv + qgelu as 9 tap-GEMMs.
// block = (b, 2-row tile): 896 blocks x 256 threads (4 waves, N-split).
// Halo LDS: [kc(2)][(r*58+c)][40] bf16, 4 rows -> 37.1 KB -> 4 blocks/CU.
// XCD swizzle (896 = 8*112).
// ---------------------------------------------------------------------------
__global__ __launch_bounds__(256, 4) void k4_conv(
    const ushort_t* __restrict__ xpg, const ushort_t* __restrict__ cwb,
    ushort_t* __restrict__ xd2g)
{
    __shared__ ushort_t xs[2 * 232 * 40];   // 37,120 B; reused as epilogue buf

    const int tid = threadIdx.x;
    const int bid = blockIdx.x;
    const int swz = (bid & 7) * 112 + (bid >> 3);   // bijective: 896 % 8 == 0
    const int b = swz / 28, yt = swz % 28, y0 = yt * 2;

    // stage haloed input: 4 rows x 58 cols x 8 chunks = 1856
    for (int u = tid; u < 1856; u += 256) {
        int r = u / 464, rem = u % 464, c = rem >> 3, c8 = rem & 7;
        int gy = y0 - 1 + r, gx = c - 1;
        uint4 v = make_uint4(0, 0, 0, 0);
        if (gy >= 0 && gy < 56 && gx >= 0 && gx < 56)
            v = *(const uint4*)(xpg + ((size_t)b * HW_ + gy * 56 + gx) * 64 + c8 * 8);
        int kc = c8 >> 2, q = c8 & 3;
        *(uint4*)&xs[kc * 9280 + (r * 58 + c) * 40 + q * 8] = v;
    }
    __syncthreads();

    const int lane = tid & 63, wv = tid >> 6;   // wv = output-channel tile nt
    const int col = lane & 15, q = lane >> 4;

    // per-M-tile lane base byte-offsets (dy=dx=0 corner); 7 tiles = 2 rows
    int abase[7];
    #pragma unroll
    for (int t = 0; t < 7; t++) {
        int p = t * 16 + col;
        int row = p / 56, cc = p - row * 56;
        abase[t] = ((row * 58 + cc) * 40 + q * 8) * 2;
    }

    f32x4 acc[7];
    #pragma unroll
    for (int t = 0; t < 7; t++) acc[t] = (f32x4)0.0f;

    const ushort_t* wbase = cwb + (size_t)b * 36864;
    #pragma unroll
    for (int tap = 0; tap < 9; tap++) {
        const int dy = tap / 3, dx = tap % 3;       // constants after unroll
        const int toff = (dy * 58 + dx) * 80;
        bf16x8 Bf0 = *(const bf16x8*)(wbase + tap * 4096 + ((0 * 4 + wv) * 64 + lane) * 8);
        bf16x8 Bf1 = *(const bf16x8*)(wbase + tap * 4096 + ((1 * 4 + wv) * 64 + lane) * 8);
        #pragma unroll
        for (int t = 0; t < 7; t++) {
            bf16x8 A0 = *(const bf16x8*)((const char*)xs + abase[t] + toff);
            bf16x8 A1 = *(const bf16x8*)((const char*)xs + 18560 + abase[t] + toff);
            acc[t] = MFMA(A0, Bf0, acc[t]);
            acc[t] = MFMA(A1, Bf1, acc[t]);
        }
    }
    __syncthreads();   // done with halo; reuse xs as epilogue buffer [112][72]

    #pragma unroll
    for (int t = 0; t < 7; t++)
        #pragma unroll
        for (int r = 0; r < 4; r++)
            xs[(t * 16 + q * 4 + r) * 72 + wv * 16 + col] = f2bf(qgelu(acc[t][r]));
    __syncthreads();

    // coalesced write-out: 112 pos x 8 chunks = 896
    for (int u = tid; u < 896; u += 256) {
        int pos = u >> 3, c8 = u & 7;
        uint4 v = *(const uint4*)&xs[pos * 72 + c8 * 8];
        size_t gpos = (size_t)b * HW_ + (size_t)y0 * 56 + pos;
        *(uint4*)(xd2g + gpos * 64 + c8 * 8) = v;
    }
}

// ---------------------------------------------------------------------------
// K5 (MFMA) v2: out = xd2@Wu^T + bu + x. wuf staged in LDS (kills 24
// serialized global B-loads/wave). LDS 33.8 KB -> 4 blocks/CU.
// ---------------------------------------------------------------------------
__global__ __launch_bounds__(256, 4) void k5_up_res(
    const ushort_t* __restrict__ xd2g, const ushort_t* __restrict__ wuf,
    const float* __restrict__ bu, const float* __restrict__ xg,
    float* __restrict__ outg)
{
    __shared__ ushort_t xds[64 * 72];     // 9,216 B
    __shared__ ushort_t wsh[12288];       // 24,576 B

    const int tid = threadIdx.x;
    const size_t posBase = (size_t)blockIdx.x * 64;

    // stage wuf -> LDS
    {
        uint4* d = (uint4*)wsh;
        const uint4* s = (const uint4*)wuf;
        for (int u = tid; u < 1536; u += 256) d[u] = s[u];
    }
    // stage xd2 tile
    #pragma unroll
    for (int t = 0; t < 2; t++) {
        int u = tid + t * 256;
        int pos = u >> 3, c8 = u & 7;
        uint4 v = *(const uint4*)(xd2g + (posBase + pos) * 64 + c8 * 8);
        *(uint4*)&xds[pos * 72 + c8 * 8] = v;
    }
    __syncthreads();

    const int lane = tid & 63, wv = tid >> 6;
    const int col = lane & 15, q = lane >> 4;

    bf16x8 A[2];
    #pragma unroll
    for (int kc = 0; kc < 2; kc++)
        A[kc] = *(const bf16x8*)&xds[(wv * 16 + col) * 72 + kc * 32 + q * 8];

    f32x4 acc[12];
    #pragma unroll
    for (int nt = 0; nt < 12; nt++) acc[nt] = (f32x4)0.0f;
    #pragma unroll
    for (int kc = 0; kc < 2; kc++)
        #pragma unroll
        for (int nt = 0; nt < 12; nt++) {
            bf16x8 B = *(const bf16x8*)&wsh[((kc * 12 + nt) * 64 + lane) * 8];
            acc[nt] = MFMA(A[kc], B, acc[nt]);
        }

    #pragma unroll
    for (int nt = 0; nt < 12; nt++) {
        float bias = bu[nt * 16 + col];
        #pragma unroll
        for (int r = 0; r < 4; r++) {
            size_t off = (posBase + wv * 16 + q * 4 + r) * 192 + nt * 16 + col;
            outg[off] = acc[nt][r] + bias + xg[off];
        }
    }
}

// ---------------------------------------------------------------------------
extern "C" void kernel_launch(void* const* d_in, const int* in_sizes, int n_in,
                              void* d_out, int out_size, void* d_ws, size_t ws_size,
                              hipStream_t stream) {
    const float* x    = (const float*)d_in[0];
    const float* W1   = (const float*)d_in[1];
    const float* b1   = (const float*)d_in[2];
    const float* W2   = (const float*)d_in[3];
    const float* b2   = (const float*)d_in[4];
    const float* mtok = (const float*)d_in[5];
    const float* Wh   = (const float*)d_in[6];
    const float* bh   = (const float*)d_in[7];
    const float* Wd   = (const float*)d_in[8];
    const float* bd   = (const float*)d_in[9];
    const float* Wu   = (const float*)d_in[10];
    const float* bu   = (const float*)d_in[11];
    float* out = (float*)d_out;

    char* ws = (char*)d_ws;
    ushort_t* pf2 = (ushort_t*)ws;                        // 12,845,056 B
    ushort_t* xp  = (ushort_t*)(ws + 12845056);           // 12,845,056 B
    ushort_t* xd2 = pf2;                                  // alias: pf2 dead after k2c
    ushort_t* cwb = (ushort_t*)(ws + 25690112);           //  2,359,296 B
    float*    mwf = (float*)(ws + 28049408);              //      8,192 B
    float*    Lg  = (float*)(ws + 28057600);              //  3,211,264 B
    ushort_t* w1f = (ushort_t*)(ws + 31268864);           //     24,576 B
    ushort_t* wdf = (ushort_t*)(ws + 31293440);           //     24,576 B
    ushort_t* w2f = (ushort_t*)(ws + 31318016);           //      8,192 B
    ushort_t* mtf = (ushort_t*)(ws + 31326208);           //      2,048 B
    ushort_t* wuf = (ushort_t*)(ws + 31328256);           //     24,576 B
    float*    Pmax= (float*)(ws + 31352832);              //      8,192 B
    float*    Psum= (float*)(ws + 31361024);              //      8,192 B
    float*    smxg= (float*)(ws + 31369216);              //      1,024 B
    float*    sinvg=(float*)(ws + 31370240);              //      1,024 B

    k0_prep<<<48, 256, 0, stream>>>(W1, W2, mtok, Wd, Wu, w1f, wdf, w2f, mtf, wuf);
    k1_meta_adapter<<<1568, 256, 0, stream>>>(x, b1, b2, bd, w1f, wdf, w2f, mtf,
                                              pf2, xp, Lg);
    k2a_partial<<<256, 256, 0, stream>>>(Lg, Pmax, Psum);
    k2b_combine<<<1, 256, 0, stream>>>(Pmax, Psum, smxg, sinvg, mwf);
    k2c_mwf<<<256, 256, 0, stream>>>(Lg, pf2, smxg, sinvg, mwf);
    k3_hypernet<<<576, 256, 0, stream>>>(mwf, Wh, bh, cwb);
    k4_conv<<<896, 256, 0, stream>>>(xp, cwb, xd2);
    k5_up_res<<<1568, 256, 0, stream>>>(xd2, wuf, bu, x, out);
}

// Round 4
// 241.275 us; speedup vs baseline: 1.0280x; 1.0280x over previous
//
#include <hip/hip_runtime.h>

typedef unsigned short ushort_t;
typedef short bf16x8 __attribute__((ext_vector_type(8)));
typedef float f32x4 __attribute__((ext_vector_type(4)));

#define MFMA(a, b, c) __builtin_amdgcn_mfma_f32_16x16x32_bf16(a, b, c, 0, 0, 0)

#define B_    32
#define HW_   3136
#define NPOS  100352

__device__ __forceinline__ float bf2f(unsigned short h) {
    return __uint_as_float(((unsigned int)h) << 16);
}
__device__ __forceinline__ unsigned short f2bf(float f) {
    unsigned int u = __float_as_uint(f);
    u += 0x7FFFu + ((u >> 16) & 1u);
    return (unsigned short)(u >> 16);
}
__device__ __forceinline__ float qgelu(float v) {
    return v / (1.0f + __expf(-1.702f * v));
}
__device__ __forceinline__ void unpack8(uint4 v, float* f) {
    f[0] = bf2f((unsigned short)(v.x & 0xffff)); f[1] = bf2f((unsigned short)(v.x >> 16));
    f[2] = bf2f((unsigned short)(v.y & 0xffff)); f[3] = bf2f((unsigned short)(v.y >> 16));
    f[4] = bf2f((unsigned short)(v.z & 0xffff)); f[5] = bf2f((unsigned short)(v.z >> 16));
    f[6] = bf2f((unsigned short)(v.w & 0xffff)); f[7] = bf2f((unsigned short)(v.w >> 16));
}

// ---------------------------------------------------------------------------
// K0: pack weights into MFMA B-fragment order (bf16).
// B-frag for (kc,nt): lane holds B[k=kc*32+(lane>>4)*8+j][n=nt*16+(lane&15)].
// Stored flat: [frag-linear][lane][8].
// ---------------------------------------------------------------------------
__global__ __launch_bounds__(256) void k0_prep(
    const float* __restrict__ W1, const float* __restrict__ W2,
    const float* __restrict__ mtok, const float* __restrict__ Wd,
    const float* __restrict__ Wu,
    ushort_t* __restrict__ w1f, ushort_t* __restrict__ wdf,
    ushort_t* __restrict__ w2f, ushort_t* __restrict__ mtf,
    ushort_t* __restrict__ wuf)
{
    const int gid = blockIdx.x * 256 + threadIdx.x;
    const int stride = gridDim.x * 256;
    // W1 / Wd: K=192 (6 kc) x N=64 (4 nt): 6*4*64*8 = 12288
    for (int i = gid; i < 12288; i += stride) {
        int j = i & 7, lane = (i >> 3) & 63, nt = (i >> 9) & 3, kc = i >> 11;
        int n = nt * 16 + (lane & 15), k = kc * 32 + (lane >> 4) * 8 + j;
        w1f[i] = f2bf(W1[n * 192 + k]);
        wdf[i] = f2bf(Wd[n * 192 + k]);
    }
    // W2: K=64 (2 kc) x N=64 (4 nt): 4096
    for (int i = gid; i < 4096; i += stride) {
        int j = i & 7, lane = (i >> 3) & 63, nt = (i >> 9) & 3, kc = i >> 11;
        int n = nt * 16 + (lane & 15), k = kc * 32 + (lane >> 4) * 8 + j;
        w2f[i] = f2bf(W2[n * 64 + k]);
    }
    // mask_token: K=64 (2 kc) x N=8 padded to 16: 2*64*8 = 1024
    for (int i = gid; i < 1024; i += stride) {
        int j = i & 7, lane = (i >> 3) & 63, kc = i >> 9;
        int n = lane & 15, k = kc * 32 + (lane >> 4) * 8 + j;
        mtf[i] = (n < 8) ? f2bf(mtok[n * 64 + k]) : (ushort_t)0;
    }
    // Wu: K=64 (2 kc) x N=192 (12 nt): 2*12*64*8 = 12288
    for (int i = gid; i < 12288; i += stride) {
        int j = i & 7, lane = (i >> 3) & 63, g = i >> 9;
        int nt = g % 12, kc = g / 12;
        int n = nt * 16 + (lane & 15), k = kc * 32 + (lane >> 4) * 8 + j;
        wuf[i] = f2bf(Wu[n * 64 + k]);
    }
}

// ---------------------------------------------------------------------------
// K1 (MFMA), v4: ILP-first. 1568 blocks x 64 threads (1 wave). Each wave owns
// M=64 positions (4 M-tiles of 16): every B-fragment load (global, L2-hot
// 59 KB shared by all waves) is reused 4x, and there are 16 independent
// accumulator chains, so the fully-unrolled loop hides VMEM latency inside
// the wave. No barriers, no cross-wave LDS; only a 2.3 KB per-wave epilogue
// buffer. __launch_bounds__(64,2): VGPR cap 256 (acc alone is 128).
// ---------------------------------------------------------------------------
__global__ __launch_bounds__(64, 2) void k1_meta_adapter(
    const float* __restrict__ x, const float* __restrict__ b1,
    const float* __restrict__ b2, const float* __restrict__ bd,
    const ushort_t* __restrict__ w1f, const ushort_t* __restrict__ wdf,
    const ushort_t* __restrict__ w2f, const ushort_t* __restrict__ mtf,
    ushort_t* __restrict__ pf2g, ushort_t* __restrict__ xpg,
    float* __restrict__ Lg)
{
    __shared__ ushort_t buf[16 * 72];   // 2,304 B per-wave epilogue buffer

    const int lane = threadIdx.x;
    const int col = lane & 15, q = lane >> 4;
    const int posBase = blockIdx.x * 64;

    // biases (per-lane, col-indexed), hoisted out of the m-loop
    float bias1[4], biasd[4], bias2[4];
    #pragma unroll
    for (int nt = 0; nt < 4; nt++) {
        bias1[nt] = b1[nt * 16 + col];
        biasd[nt] = bd[nt * 16 + col];
        bias2[nt] = b2[nt * 16 + col];
    }

    f32x4 acc1[4][4], acc3[4][4];       // [m][nt]
    #pragma unroll
    for (int m = 0; m < 4; m++)
        #pragma unroll
        for (int nt = 0; nt < 4; nt++) { acc1[m][nt] = (f32x4)0.0f; acc3[m][nt] = (f32x4)0.0f; }

    // GEMM1 (x@W1^T) + GEMM3 (x@Wd^T): K=192 in 6 steps; 4 M-tiles per wave.
    #pragma unroll
    for (int kc = 0; kc < 6; kc++) {
        bf16x8 A[4];
        #pragma unroll
        for (int m = 0; m < 4; m++) {
            const float4* gp = (const float4*)(x +
                (size_t)(posBase + m * 16 + col) * 192 + kc * 32 + q * 8);
            float4 v0 = gp[0], v1 = gp[1];
            A[m][0] = (short)f2bf(v0.x); A[m][1] = (short)f2bf(v0.y);
            A[m][2] = (short)f2bf(v0.z); A[m][3] = (short)f2bf(v0.w);
            A[m][4] = (short)f2bf(v1.x); A[m][5] = (short)f2bf(v1.y);
            A[m][6] = (short)f2bf(v1.z); A[m][7] = (short)f2bf(v1.w);
        }
        #pragma unroll
        for (int nt = 0; nt < 4; nt++) {
            bf16x8 B1 = *(const bf16x8*)(w1f + ((kc * 4 + nt) * 64 + lane) * 8);
            #pragma unroll
            for (int m = 0; m < 4; m++) acc1[m][nt] = MFMA(A[m], B1, acc1[m][nt]);
            bf16x8 Bd = *(const bf16x8*)(wdf + ((kc * 4 + nt) * 64 + lane) * 8);
            #pragma unroll
            for (int m = 0; m < 4; m++) acc3[m][nt] = MFMA(A[m], Bd, acc3[m][nt]);
        }
    }

    // Per-M-tile epilogue, sequenced through the per-wave buffer:
    // pf1 -> GEMM2 -> xp -> store xp -> pf2 -> logits -> store pf2.
    #pragma unroll
    for (int m = 0; m < 4; m++) {
        const int rowBase = posBase + m * 16;

        // pf1 = relu(acc1 + b1) -> buf
        #pragma unroll
        for (int nt = 0; nt < 4; nt++)
            #pragma unroll
            for (int r = 0; r < 4; r++) {
                float v = acc1[m][nt][r] + bias1[nt];
                v = v > 0.0f ? v : 0.0f;
                buf[(q * 4 + r) * 72 + nt * 16 + col] = f2bf(v);
            }

        // GEMM2: pf2 = pf1 @ W2^T (B-frags global, L1/L2-hot)
        f32x4 acc2[4];
        #pragma unroll
        for (int nt = 0; nt < 4; nt++) acc2[nt] = (f32x4)0.0f;
        #pragma unroll
        for (int kc = 0; kc < 2; kc++) {
            bf16x8 A2 = *(const bf16x8*)&buf[col * 72 + kc * 32 + q * 8];
            #pragma unroll
            for (int nt = 0; nt < 4; nt++) {
                bf16x8 B2 = *(const bf16x8*)(w2f + ((kc * 4 + nt) * 64 + lane) * 8);
                acc2[nt] = MFMA(A2, B2, acc2[nt]);
            }
        }

        // xp = qgelu(acc3 + bd) -> buf (pf1 dead)
        #pragma unroll
        for (int nt = 0; nt < 4; nt++)
            #pragma unroll
            for (int r = 0; r < 4; r++) {
                float v = qgelu(acc3[m][nt][r] + biasd[nt]);
                buf[(q * 4 + r) * 72 + nt * 16 + col] = f2bf(v);
            }

        // write xp: 16 pos x 8 chunks, 2 per lane
        #pragma unroll
        for (int t = 0; t < 2; t++) {
            int idx = lane + t * 64;
            int pos = idx >> 3, c8 = idx & 7;
            uint4 vx = *(const uint4*)&buf[pos * 72 + c8 * 8];
            *(uint4*)(xpg + ((size_t)(rowBase + pos)) * 64 + c8 * 8) = vx;
        }

        // pf2 (+b2) -> buf (xp dead)
        #pragma unroll
        for (int nt = 0; nt < 4; nt++)
            #pragma unroll
            for (int r = 0; r < 4; r++)
                buf[(q * 4 + r) * 72 + nt * 16 + col] = f2bf(acc2[nt][r] + bias2[nt]);

        // logits: L = pf2 @ mtok^T (N=8 padded to 16)
        f32x4 Lacc = (f32x4)0.0f;
        #pragma unroll
        for (int kc = 0; kc < 2; kc++) {
            bf16x8 A3 = *(const bf16x8*)&buf[col * 72 + kc * 32 + q * 8];
            bf16x8 Bm = *(const bf16x8*)(mtf + (kc * 64 + lane) * 8);
            Lacc = MFMA(A3, Bm, Lacc);
        }
        if (col < 8) {
            #pragma unroll
            for (int r = 0; r < 4; r++)
                Lg[((size_t)(rowBase + q * 4 + r)) * 8 + col] = Lacc[r];
        }

        // write pf2
        #pragma unroll
        for (int t = 0; t < 2; t++) {
            int idx = lane + t * 64;
            int pos = idx >> 3, c8 = idx & 7;
            uint4 vp = *(const uint4*)&buf[pos * 72 + c8 * 8];
            *(uint4*)(pf2g + ((size_t)(rowBase + pos)) * 64 + c8 * 8) = vp;
        }
    }
}

// ---------------------------------------------------------------------------
// K2a: per-(b, slice) partial softmax stats. 256 blocks (b = blk/8, sl = blk%8),
// 392 positions per slice. Writes Pmax/Psum [32][8][8].
// ---------------------------------------------------------------------------
__global__ __launch_bounds__(256) void k2a_partial(
    const float* __restrict__ Lg, float* __restrict__ Pmax, float* __restrict__ Psum)
{
    __shared__ float wred[4][8];
    __shared__ float Msh[8];

    const int tid = threadIdx.x;
    const int b = blockIdx.x >> 3, sl = blockIdx.x & 7;
    const int lane = tid & 63, wv = tid >> 6;
    const float* Lb = Lg + ((size_t)b * HW_ + (size_t)sl * 392) * 8;

    float l0[8], l1[8];
    {
        const float4* p = (const float4*)(Lb + (size_t)tid * 8);
        float4 a = p[0], c = p[1];
        l0[0] = a.x; l0[1] = a.y; l0[2] = a.z; l0[3] = a.w;
        l0[4] = c.x; l0[5] = c.y; l0[6] = c.z; l0[7] = c.w;
    }
    if (tid < 136) {
        const float4* p = (const float4*)(Lb + (size_t)(tid + 256) * 8);
        float4 a = p[0], c = p[1];
        l1[0] = a.x; l1[1] = a.y; l1[2] = a.z; l1[3] = a.w;
        l1[4] = c.x; l1[5] = c.y; l1[6] = c.z; l1[7] = c.w;
    } else {
        #pragma unroll
        for (int m = 0; m < 8; m++) l1[m] = -1e30f;
    }

    float lm[8];
    #pragma unroll
    for (int m = 0; m < 8; m++) {
        float v = fmaxf(l0[m], l1[m]);
        for (int off = 32; off > 0; off >>= 1) v = fmaxf(v, __shfl_down(v, off));
        lm[m] = v;
    }
    if (lane == 0) {
        #pragma unroll
        for (int m = 0; m < 8; m++) wred[wv][m] = lm[m];
    }
    __syncthreads();
    if (tid < 8)
        Msh[tid] = fmaxf(fmaxf(wred[0][tid], wred[1][tid]), fmaxf(wred[2][tid], wred[3][tid]));
    __syncthreads();

    float s[8];
    #pragma unroll
    for (int m = 0; m < 8; m++)
        s[m] = __expf(l0[m] - Msh[m]) + __expf(l1[m] - Msh[m]);   // l1=-1e30 -> 0
    #pragma unroll
    for (int m = 0; m < 8; m++) {
        float v = s[m];
        for (int off = 32; off > 0; off >>= 1) v += __shfl_down(v, off);
        s[m] = v;
    }
    __syncthreads();
    if (lane == 0) {
        #pragma unroll
        for (int m = 0; m < 8; m++) wred[wv][m] = s[m];
    }
    __syncthreads();
    if (tid < 8) {
        Psum[((size_t)b * 8 + sl) * 8 + tid] =
            wred[0][tid] + wred[1][tid] + wred[2][tid] + wred[3][tid];
        Pmax[((size_t)b * 8 + sl) * 8 + tid] = Msh[tid];
    }
}

// ---------------------------------------------------------------------------
// K2b: combine slice partials -> smx/sinv per (b,m); zero mwf. 1 block.
// ---------------------------------------------------------------------------
__global__ __launch_bounds__(256) void k2b_combine(
    const float* __restrict__ Pmax, const float* __restrict__ Psum,
    float* __restrict__ smxg, float* __restrict__ sinvg, float* __restrict__ mwfg)
{
    const int tid = threadIdx.x;        // 256 = 32 b x 8 m
    const int b = tid >> 3, m = tid & 7;
    float M = -1e30f;
    #pragma unroll
    for (int sl = 0; sl < 8; sl++)
        M = fmaxf(M, Pmax[((size_t)b * 8 + sl) * 8 + m]);
    float S = 0.0f;
    #pragma unroll
    for (int sl = 0; sl < 8; sl++)
        S += Psum[((size_t)b * 8 + sl) * 8 + m] * __expf(Pmax[((size_t)b * 8 + sl) * 8 + m] - M);
    smxg[tid] = M;
    sinvg[tid] = 1.0f / S;
    for (int i = tid; i < 2048; i += 256) mwfg[i] = 0.0f;
}

// ---------------------------------------------------------------------------
// K2c: masksum per slice + weighted pf2 reduction, atomicAdd into mwf.
// 256 blocks (b = blk/8, sl = blk%8).
// ---------------------------------------------------------------------------
__global__ __launch_bounds__(256) void k2c_mwf(
    const float* __restrict__ Lg, const ushort_t* __restrict__ pf2g,
    const float* __restrict__ smxg, const float* __restrict__ sinvg,
    float* __restrict__ mwfg)
{
    __shared__ float ms[392];
    __shared__ float sred[32 * 64];

    const int tid = threadIdx.x;
    const int b = blockIdx.x >> 3, sl = blockIdx.x & 7;
    const size_t base = (size_t)b * HW_ + (size_t)sl * 392;

    float smx[8], sinv[8];
    #pragma unroll
    for (int m = 0; m < 8; m++) {
        smx[m] = smxg[b * 8 + m];
        sinv[m] = sinvg[b * 8 + m];
    }

    for (int lp = tid; lp < 392; lp += 256) {
        const float4* p = (const float4*)(Lg + (base + lp) * 8);
        float4 a = p[0], c = p[1];
        ms[lp] = __expf(a.x - smx[0]) * sinv[0] + __expf(a.y - smx[1]) * sinv[1]
               + __expf(a.z - smx[2]) * sinv[2] + __expf(a.w - smx[3]) * sinv[3]
               + __expf(c.x - smx[4]) * sinv[4] + __expf(c.y - smx[5]) * sinv[5]
               + __expf(c.z - smx[6]) * sinv[6] + __expf(c.w - smx[7]) * sinv[7];
    }
    __syncthreads();

    const int part = tid >> 3, kg = tid & 7;
    float a8[8];
    #pragma unroll
    for (int j = 0; j < 8; j++) a8[j] = 0.0f;
    for (int lp = part; lp < 392; lp += 32) {
        float w = ms[lp];
        uint4 v = *(const uint4*)(pf2g + (base + lp) * 64 + kg * 8);
        float f[8]; unpack8(v, f);
        #pragma unroll
        for (int j = 0; j < 8; j++) a8[j] += w * f[j];
    }
    #pragma unroll
    for (int j = 0; j < 8; j++) sred[part * 64 + kg * 8 + j] = a8[j];
    __syncthreads();
    if (tid < 64) {
        float s = 0.0f;
        #pragma unroll
        for (int pt = 0; pt < 32; pt++) s += sred[pt * 64 + tid];
        atomicAdd(&mwfg[b * 64 + tid], s);
    }
}

// ---------------------------------------------------------------------------
// K3 v2: conv_w = mwf@Wh^T + bh in k4's B-frag order. 4-way b-split for
// occupancy: 576 blocks x 256 threads, thread = (op 64/block, b-quad 4).
// 2-accumulator inner loop breaks the serial FMA chain.
// ---------------------------------------------------------------------------
__global__ __launch_bounds__(256) void k3_hypernet(
    const float* __restrict__ mwfg, const float* __restrict__ Whg,
    const float* __restrict__ bhg, ushort_t* __restrict__ cwb)
{
    __shared__ float mwfs[32 * 64];
    const int tid = threadIdx.x;
    for (int i = tid; i < 2048; i += 256) mwfs[i] = mwfg[i];
    __syncthreads();

    const int op = blockIdx.x * 64 + (tid >> 2);   // 0..36863
    const int bq = tid & 3;                        // b-quad: b in [bq*8, bq*8+8)
    const int j = op & 7, lane = (op >> 3) & 63, nt = (op >> 9) & 3;
    const int kc = (op >> 11) & 1, tap = op >> 12;
    const int oc = nt * 16 + (lane & 15);
    const int ic = kc * 32 + (lane >> 4) * 8 + j;
    const int o = oc * 576 + ic * 9 + tap;     // Wh row

    float wreg[64];
    const float4* src = (const float4*)(Whg + (size_t)o * 64);
    #pragma unroll
    for (int t = 0; t < 16; t++) {
        float4 v = src[t];
        wreg[t * 4 + 0] = v.x; wreg[t * 4 + 1] = v.y;
        wreg[t * 4 + 2] = v.z; wreg[t * 4 + 3] = v.w;
    }
    const float bias = bhg[o];
    #pragma unroll
    for (int i = 0; i < 8; i += 2) {
        int b0 = bq * 8 + i, b1 = b0 + 1;
        float a0 = bias, a1 = bias;
        #pragma unroll
        for (int k = 0; k < 64; k++) {
            a0 += mwfs[b0 * 64 + k] * wreg[k];
            a1 += mwfs[b1 * 64 + k] * wreg[k];
        }
        cwb[(size_t)b0 * 36864 + op] = f2bf(a0);
        cwb[(size_t)b1 * 36864 + op] = f2bf(a1);
    }
}

// ---------------------------------------------------------------------------
// K4 (MFMA): per-sample 3x3 conv + qgelu as 9 tap-GEMMs.
// block = (b, 2-row tile): 896 blocks x 256 threads (4 waves, N-split).
// Halo LDS: [kc(2)][(r*58+c)][40] bf16, 4 rows -> 37.1 KB -> 4 blocks/CU.
// XCD swizzle (896 = 8*112).
// ---------------------------------------------------------------------------
__global__ __launch_bounds__(256, 4) void k4_conv(
    const ushort_t* __restrict__ xpg, const ushort_t* __restrict__ cwb,
    ushort_t* __restrict__ xd2g)
{
    __shared__ ushort_t xs[2 * 232 * 40];   // 37,120 B; reused as epilogue buf

    const int tid = threadIdx.x;
    const int bid = blockIdx.x;
    const int swz = (bid & 7) * 112 + (bid >> 3);   // bijective: 896 % 8 == 0
    const int b = swz / 28, yt = swz % 28, y0 = yt * 2;

    // stage haloed input: 4 rows x 58 cols x 8 chunks = 1856
    for (int u = tid; u < 1856; u += 256) {
        int r = u / 464, rem = u % 464, c = rem >> 3, c8 = rem & 7;
        int gy = y0 - 1 + r, gx = c - 1;
        uint4 v = make_uint4(0, 0, 0, 0);
        if (gy >= 0 && gy < 56 && gx >= 0 && gx < 56)
            v = *(const uint4*)(xpg + ((size_t)b * HW_ + gy * 56 + gx) * 64 + c8 * 8);
        int kc = c8 >> 2, q = c8 & 3;
        *(uint4*)&xs[kc * 9280 + (r * 58 + c) * 40 + q * 8] = v;
    }
    __syncthreads();

    const int lane = tid & 63, wv = tid >> 6;   // wv = output-channel tile nt
    const int col = lane & 15, q = lane >> 4;

    // per-M-tile lane base byte-offsets (dy=dx=0 corner); 7 tiles = 2 rows
    int abase[7];
    #pragma unroll
    for (int t = 0; t < 7; t++) {
        int p = t * 16 + col;
        int row = p / 56, cc = p - row * 56;
        abase[t] = ((row * 58 + cc) * 40 + q * 8) * 2;
    }

    f32x4 acc[7];
    #pragma unroll
    for (int t = 0; t < 7; t++) acc[t] = (f32x4)0.0f;

    const ushort_t* wbase = cwb + (size_t)b * 36864;
    #pragma unroll
    for (int tap = 0; tap < 9; tap++) {
        const int dy = tap / 3, dx = tap % 3;       // constants after unroll
        const int toff = (dy * 58 + dx) * 80;
        bf16x8 Bf0 = *(const bf16x8*)(wbase + tap * 4096 + ((0 * 4 + wv) * 64 + lane) * 8);
        bf16x8 Bf1 = *(const bf16x8*)(wbase + tap * 4096 + ((1 * 4 + wv) * 64 + lane) * 8);
        #pragma unroll
        for (int t = 0; t < 7; t++) {
            bf16x8 A0 = *(const bf16x8*)((const char*)xs + abase[t] + toff);
            bf16x8 A1 = *(const bf16x8*)((const char*)xs + 18560 + abase[t] + toff);
            acc[t] = MFMA(A0, Bf0, acc[t]);
            acc[t] = MFMA(A1, Bf1, acc[t]);
        }
    }
    __syncthreads();   // done with halo; reuse xs as epilogue buffer [112][72]

    #pragma unroll
    for (int t = 0; t < 7; t++)
        #pragma unroll
        for (int r = 0; r < 4; r++)
            xs[(t * 16 + q * 4 + r) * 72 + wv * 16 + col] = f2bf(qgelu(acc[t][r]));
    __syncthreads();

    // coalesced write-out: 112 pos x 8 chunks = 896
    for (int u = tid; u < 896; u += 256) {
        int pos = u >> 3, c8 = u & 7;
        uint4 v = *(const uint4*)&xs[pos * 72 + c8 * 8];
        size_t gpos = (size_t)b * HW_ + (size_t)y0 * 56 + pos;
        *(uint4*)(xd2g + gpos * 64 + c8 * 8) = v;
    }
}

// ---------------------------------------------------------------------------
// K5 (MFMA) v2: out = xd2@Wu^T + bu + x. wuf staged in LDS (kills 24
// serialized global B-loads/wave). LDS 33.8 KB -> 4 blocks/CU.
// ---------------------------------------------------------------------------
__global__ __launch_bounds__(256, 4) void k5_up_res(
    const ushort_t* __restrict__ xd2g, const ushort_t* __restrict__ wuf,
    const float* __restrict__ bu, const float* __restrict__ xg,
    float* __restrict__ outg)
{
    __shared__ ushort_t xds[64 * 72];     // 9,216 B
    __shared__ ushort_t wsh[12288];       // 24,576 B

    const int tid = threadIdx.x;
    const size_t posBase = (size_t)blockIdx.x * 64;

    // stage wuf -> LDS
    {
        uint4* d = (uint4*)wsh;
        const uint4* s = (const uint4*)wuf;
        for (int u = tid; u < 1536; u += 256) d[u] = s[u];
    }
    // stage xd2 tile
    #pragma unroll
    for (int t = 0; t < 2; t++) {
        int u = tid + t * 256;
        int pos = u >> 3, c8 = u & 7;
        uint4 v = *(const uint4*)(xd2g + (posBase + pos) * 64 + c8 * 8);
        *(uint4*)&xds[pos * 72 + c8 * 8] = v;
    }
    __syncthreads();

    const int lane = tid & 63, wv = tid >> 6;
    const int col = lane & 15, q = lane >> 4;

    bf16x8 A[2];
    #pragma unroll
    for (int kc = 0; kc < 2; kc++)
        A[kc] = *(const bf16x8*)&xds[(wv * 16 + col) * 72 + kc * 32 + q * 8];

    f32x4 acc[12];
    #pragma unroll
    for (int nt = 0; nt < 12; nt++) acc[nt] = (f32x4)0.0f;
    #pragma unroll
    for (int kc = 0; kc < 2; kc++)
        #pragma unroll
        for (int nt = 0; nt < 12; nt++) {
            bf16x8 B = *(const bf16x8*)&wsh[((kc * 12 + nt) * 64 + lane) * 8];
            acc[nt] = MFMA(A[kc], B, acc[nt]);
        }

    #pragma unroll
    for (int nt = 0; nt < 12; nt++) {
        float bias = bu[nt * 16 + col];
        #pragma unroll
        for (int r = 0; r < 4; r++) {
            size_t off = (posBase + wv * 16 + q * 4 + r) * 192 + nt * 16 + col;
            outg[off] = acc[nt][r] + bias + xg[off];
        }
    }
}

// ---------------------------------------------------------------------------
extern "C" void kernel_launch(void* const* d_in, const int* in_sizes, int n_in,
                              void* d_out, int out_size, void* d_ws, size_t ws_size,
                              hipStream_t stream) {
    const float* x    = (const float*)d_in[0];
    const float* W1   = (const float*)d_in[1];
    const float* b1   = (const float*)d_in[2];
    const float* W2   = (const float*)d_in[3];
    const float* b2   = (const float*)d_in[4];
    const float* mtok = (const float*)d_in[5];
    const float* Wh   = (const float*)d_in[6];
    const float* bh   = (const float*)d_in[7];
    const float* Wd   = (const float*)d_in[8];
    const float* bd   = (const float*)d_in[9];
    const float* Wu   = (const float*)d_in[10];
    const float* bu   = (const float*)d_in[11];
    float* out = (float*)d_out;

    char* ws = (char*)d_ws;
    ushort_t* pf2 = (ushort_t*)ws;                        // 12,845,056 B
    ushort_t* xp  = (ushort_t*)(ws + 12845056);           // 12,845,056 B
    ushort_t* xd2 = pf2;                                  // alias: pf2 dead after k2c
    ushort_t* cwb = (ushort_t*)(ws + 25690112);           //  2,359,296 B
    float*    mwf = (float*)(ws + 28049408);              //      8,192 B
    float*    Lg  = (float*)(ws + 28057600);              //  3,211,264 B
    ushort_t* w1f = (ushort_t*)(ws + 31268864);           //     24,576 B
    ushort_t* wdf = (ushort_t*)(ws + 31293440);           //     24,576 B
    ushort_t* w2f = (ushort_t*)(ws + 31318016);           //      8,192 B
    ushort_t* mtf = (ushort_t*)(ws + 31326208);           //      2,048 B
    ushort_t* wuf = (ushort_t*)(ws + 31328256);           //     24,576 B
    float*    Pmax= (float*)(ws + 31352832);              //      8,192 B
    float*    Psum= (float*)(ws + 31361024);              //      8,192 B
    float*    smxg= (float*)(ws + 31369216);              //      1,024 B
    float*    sinvg=(float*)(ws + 31370240);              //      1,024 B

    k0_prep<<<48, 256, 0, stream>>>(W1, W2, mtok, Wd, Wu, w1f, wdf, w2f, mtf, wuf);
    k1_meta_adapter<<<1568, 64, 0, stream>>>(x, b1, b2, bd, w1f, wdf, w2f, mtf,
                                             pf2, xp, Lg);
    k2a_partial<<<256, 256, 0, stream>>>(Lg, Pmax, Psum);
    k2b_combine<<<1, 256, 0, stream>>>(Pmax, Psum, smxg, sinvg, mwf);
    k2c_mwf<<<256, 256, 0, stream>>>(Lg, pf2, smxg, sinvg, mwf);
    k3_hypernet<<<576, 256, 0, stream>>>(mwf, Wh, bh, cwb);
    k4_conv<<<896, 256, 0, stream>>>(xp, cwb, xd2);
    k5_up_res<<<1568, 256, 0, stream>>>(xd2, wuf, bu, x, out);
}